// Round 1
// baseline (629.084 us; speedup 1.0000x reference)
//
#include <hip/hip_runtime.h>
#include <stdint.h>

#define M_DIM 8192
#define N_DIM 4096
#define K_DIM 4096

typedef __attribute__((ext_vector_type(4))) float f32x4;
typedef __attribute__((ext_vector_type(8))) __bf16 bf16x8;

__device__ __forceinline__ unsigned short f2bf(float f) {
  unsigned int u = __builtin_bit_cast(unsigned int, f);
  u += 0x7FFFu + ((u >> 16) & 1u);   // round-to-nearest-even
  return (unsigned short)(u >> 16);
}

__device__ __forceinline__ void load16_lds(const void* g, void* l) {
  __builtin_amdgcn_global_load_lds(
      (__attribute__((address_space(1))) void*)g,
      (__attribute__((address_space(3))) void*)l,
      16, 0, 0);
}

// ---------------------------------------------------------------------------
// Kernel 1: x f32 -> bf16 (vectorized 8 elems/thread)
// ---------------------------------------------------------------------------
__global__ __launch_bounds__(256) void cvt_x_kernel(const float* __restrict__ x,
                                                    unsigned short* __restrict__ xb) {
  const int n8 = (M_DIM * K_DIM) / 8;  // 4194304
  int i = blockIdx.x * blockDim.x + threadIdx.x;
  const int stride = gridDim.x * blockDim.x;
  for (; i < n8; i += stride) {
    const float4* p = (const float4*)x + (size_t)i * 2;
    const float4 a = p[0];
    const float4 b = p[1];
    uint4 o;
    o.x = (unsigned)f2bf(a.x) | ((unsigned)f2bf(a.y) << 16);
    o.y = (unsigned)f2bf(a.z) | ((unsigned)f2bf(a.w) << 16);
    o.z = (unsigned)f2bf(b.x) | ((unsigned)f2bf(b.y) << 16);
    o.w = (unsigned)f2bf(b.z) | ((unsigned)f2bf(b.w) << 16);
    ((uint4*)xb)[i] = o;
  }
}

// ---------------------------------------------------------------------------
// Kernel 2: Wb[o][i] = bf16(W[o][i] + 2 * sum_r B[o][r]*A[r][i])
// grid (64,64): 64x64 tile of the 4096x4096 weight
// ---------------------------------------------------------------------------
__global__ __launch_bounds__(256) void build_wb_kernel(const float* __restrict__ W,
                                                       const float* __restrict__ B_lora,
                                                       const float* __restrict__ A_lora,
                                                       unsigned short* __restrict__ wb) {
  __shared__ float As[64][17];  // As[i_local][r] = A[r][i0+i_local]  (pad 17: conflict-free)
  __shared__ float Bs[64][17];  // Bs[o_local][r] = B[o0+o_local][r]
  const int t = threadIdx.x;
  const int i0 = blockIdx.x * 64;
  const int o0 = blockIdx.y * 64;
  {
    const int c = t & 63;
    #pragma unroll
    for (int rr = (t >> 6); rr < 16; rr += 4)
      As[c][rr] = A_lora[rr * K_DIM + i0 + c];
    const int r2 = t & 15;
    #pragma unroll
    for (int oo = (t >> 4); oo < 64; oo += 16)
      Bs[oo][r2] = B_lora[(o0 + oo) * 16 + r2];
  }
  __syncthreads();
  const int ci = t & 63;
  const int og = t >> 6;
  float areg[16];
  #pragma unroll
  for (int r = 0; r < 16; ++r) areg[r] = As[ci][r];
  const int i = i0 + ci;
  #pragma unroll 4
  for (int j = 0; j < 16; ++j) {
    const int ol = og * 16 + j;
    float d = 0.f;
    #pragma unroll
    for (int r = 0; r < 16; ++r) d += Bs[ol][r] * areg[r];
    const size_t idx = (size_t)(o0 + ol) * K_DIM + i;
    wb[idx] = f2bf(W[idx] + 2.0f * d);
  }
}

// ---------------------------------------------------------------------------
// Kernel 3: bf16 MFMA GEMM (m97 structure: 128x128 tile, BK=32, 4 waves 2x2,
// global_load_lds width-16, 2 barriers/K-step) + fused bias epilogue.
// out[m][n] = sum_k xb[m][k]*wb[n][k] + bias[n] + 2*dbias[n]
// ---------------------------------------------------------------------------
__global__ __launch_bounds__(256) void gemm_kernel(const unsigned short* __restrict__ xb,
                                                   const unsigned short* __restrict__ wb,
                                                   const float* __restrict__ bias,
                                                   const float* __restrict__ dbias,
                                                   float* __restrict__ out) {
  constexpr int BM = 128, BN = 128, BK = 32;
  __shared__ unsigned short As[BM * BK];  // 8 KiB, row-major [128][32]
  __shared__ unsigned short Bs[BN * BK];  // 8 KiB

  const int t = threadIdx.x;
  const int w = t >> 6, l = t & 63;
  const int nbn = N_DIM / BN;              // 32
  const int nwg = (M_DIM / BM) * nbn;      // 2048 (divisible by 8 -> bijective swizzle)
  int bid = (int)blockIdx.x;
  bid = (bid & 7) * (nwg >> 3) + (bid >> 3);  // XCD-aware swizzle
  const int m0 = (bid / nbn) * BM;
  const int n0 = (bid % nbn) * BN;
  const int wr = w >> 1, wc = w & 1;

  f32x4 acc[4][4];
  #pragma unroll
  for (int i = 0; i < 4; ++i)
    #pragma unroll
    for (int j = 0; j < 4; ++j) acc[i][j] = f32x4{0.f, 0.f, 0.f, 0.f};

  // staging: chunk q in [0,512): row = q>>2 (4 x 16B chunks per 64B row), c16 = q&3
  const int q0 = w * 64 + l, q1 = q0 + 256;
  const unsigned short* ga0 = xb + (size_t)(m0 + (q0 >> 2)) * K_DIM + (q0 & 3) * 8;
  const unsigned short* ga1 = xb + (size_t)(m0 + (q1 >> 2)) * K_DIM + (q1 & 3) * 8;
  const unsigned short* gb0 = wb + (size_t)(n0 + (q0 >> 2)) * K_DIM + (q0 & 3) * 8;
  const unsigned short* gb1 = wb + (size_t)(n0 + (q1 >> 2)) * K_DIM + (q1 & 3) * 8;
  unsigned short* la0 = As + w * 512;        // wave-uniform LDS bases (lane x 16B dest)
  unsigned short* la1 = As + (4 + w) * 512;
  unsigned short* lb0 = Bs + w * 512;
  unsigned short* lb1 = Bs + (4 + w) * 512;

  // fragment read bases: A lane l -> row=(l&15), k=8*(l>>4)+i ; same form for B
  const unsigned short* pa = As + ((wr * 64 + (l & 15)) * BK + (l >> 4) * 8);
  const unsigned short* pb = Bs + ((wc * 64 + (l & 15)) * BK + (l >> 4) * 8);

  for (int kt = 0; kt < K_DIM; kt += BK) {
    load16_lds(ga0 + kt, la0);
    load16_lds(ga1 + kt, la1);
    load16_lds(gb0 + kt, lb0);
    load16_lds(gb1 + kt, lb1);
    __syncthreads();  // compiler drains vmcnt before s_barrier
    bf16x8 af[4], bfv[4];
    #pragma unroll
    for (int mf = 0; mf < 4; ++mf) af[mf] = *(const bf16x8*)(pa + mf * 16 * BK);
    #pragma unroll
    for (int nf = 0; nf < 4; ++nf) bfv[nf] = *(const bf16x8*)(pb + nf * 16 * BK);
    #pragma unroll
    for (int mf = 0; mf < 4; ++mf)
      #pragma unroll
      for (int nf = 0; nf < 4; ++nf)
        acc[mf][nf] = __builtin_amdgcn_mfma_f32_16x16x32_bf16(af[mf], bfv[nf], acc[mf][nf], 0, 0, 0);
    __syncthreads();  // compute done before next stage overwrites
  }

  // epilogue: C/D layout col=l&15, row=4*(l>>4)+j  [m89/m91-verified]
  float bv[4];
  #pragma unroll
  for (int nf = 0; nf < 4; ++nf) {
    const int c = n0 + wc * 64 + nf * 16 + (l & 15);
    bv[nf] = bias[c] + 2.0f * dbias[c];
  }
  #pragma unroll
  for (int mf = 0; mf < 4; ++mf) {
    const int r0 = m0 + wr * 64 + mf * 16 + ((l >> 4) << 2);
    #pragma unroll
    for (int nf = 0; nf < 4; ++nf) {
      const int c = n0 + wc * 64 + nf * 16 + (l & 15);
      const f32x4 v = acc[mf][nf];
      #pragma unroll
      for (int j = 0; j < 4; ++j)
        out[(size_t)(r0 + j) * N_DIM + c] = v[j] + bv[nf];
    }
  }
}

// ---------------------------------------------------------------------------
// Fallback path (tiny workspace): xa = x @ A^T, then f32 VALU GEMM + epilogue
// ---------------------------------------------------------------------------
__global__ __launch_bounds__(256) void xa_kernel(const float* __restrict__ x,
                                                 const float* __restrict__ A_lora,
                                                 float* __restrict__ xa) {
  const int m = blockIdx.x;
  const int t = threadIdx.x;
  float acc[16];
  #pragma unroll
  for (int r = 0; r < 16; ++r) acc[r] = 0.f;
  const float* xr = x + (size_t)m * K_DIM;
  for (int k = t; k < K_DIM; k += 256) {
    const float xv = xr[k];
    #pragma unroll
    for (int r = 0; r < 16; ++r) acc[r] += xv * A_lora[r * K_DIM + k];
  }
  __shared__ float red[16][4];
  #pragma unroll
  for (int r = 0; r < 16; ++r) {
    float v = acc[r];
    for (int off = 32; off > 0; off >>= 1) v += __shfl_down(v, off, 64);
    if ((t & 63) == 0) red[r][t >> 6] = v;
  }
  __syncthreads();
  if (t < 16) xa[(size_t)m * 16 + t] = red[t][0] + red[t][1] + red[t][2] + red[t][3];
}

__global__ __launch_bounds__(256) void fgemm_kernel(const float* __restrict__ x,
                                                    const float* __restrict__ W,
                                                    const float* __restrict__ bias,
                                                    const float* __restrict__ B_lora,
                                                    const float* __restrict__ dbias,
                                                    const float* __restrict__ xa,
                                                    float* __restrict__ out) {
  __shared__ float As[64][17];
  __shared__ float Ws[64][17];
  const int t = threadIdx.x;
  const int m0 = (blockIdx.x >> 6) * 64;
  const int n0 = (blockIdx.x & 63) * 64;
  const int tx = t & 15, ty = t >> 4;
  float c[4][4] = {};
  for (int kt = 0; kt < K_DIM; kt += 16) {
    #pragma unroll
    for (int e = 0; e < 4; ++e) {
      const int q = t + e * 256;
      const int r = q >> 4, k = q & 15;
      As[r][k] = x[(size_t)(m0 + r) * K_DIM + kt + k];
      Ws[r][k] = W[(size_t)(n0 + r) * K_DIM + kt + k];
    }
    __syncthreads();
    #pragma unroll
    for (int k = 0; k < 16; ++k) {
      float a[4], b[4];
      #pragma unroll
      for (int ii = 0; ii < 4; ++ii) a[ii] = As[ty * 4 + ii][k];
      #pragma unroll
      for (int jj = 0; jj < 4; ++jj) b[jj] = Ws[tx * 4 + jj][k];
      #pragma unroll
      for (int ii = 0; ii < 4; ++ii)
        #pragma unroll
        for (int jj = 0; jj < 4; ++jj) c[ii][jj] += a[ii] * b[jj];
    }
    __syncthreads();
  }
  #pragma unroll
  for (int ii = 0; ii < 4; ++ii) {
    const int row = m0 + ty * 4 + ii;
    #pragma unroll
    for (int jj = 0; jj < 4; ++jj) {
      const int col = n0 + tx * 4 + jj;
      float d = 0.f;
      #pragma unroll
      for (int r = 0; r < 16; ++r) d += xa[(size_t)row * 16 + r] * B_lora[col * 16 + r];
      out[(size_t)row * N_DIM + col] = c[ii][jj] + 2.0f * d + bias[col] + 2.0f * dbias[col];
    }
  }
}

// ---------------------------------------------------------------------------
extern "C" void kernel_launch(void* const* d_in, const int* in_sizes, int n_in,
                              void* d_out, int out_size, void* d_ws, size_t ws_size,
                              hipStream_t stream) {
  const float* x = (const float*)d_in[0];
  const float* W = (const float*)d_in[1];
  const float* bias = (const float*)d_in[2];
  const float* B_lora = (const float*)d_in[3];
  const float* A_lora = (const float*)d_in[4];
  const float* dbias = (const float*)d_in[5];
  float* out = (float*)d_out;

  const size_t NEED = (size_t)M_DIM * K_DIM * 2 + (size_t)N_DIM * K_DIM * 2;  // 96 MiB
  if (ws_size >= NEED) {
    unsigned short* xb = (unsigned short*)d_ws;
    unsigned short* wb = xb + (size_t)M_DIM * K_DIM;
    cvt_x_kernel<<<2048, 256, 0, stream>>>(x, xb);
    build_wb_kernel<<<dim3(64, 64), 256, 0, stream>>>(W, B_lora, A_lora, wb);
    gemm_kernel<<<2048, 256, 0, stream>>>(xb, wb, bias, dbias, out);
  } else {
    float* xa = (float*)d_ws;  // 512 KiB
    xa_kernel<<<M_DIM, 256, 0, stream>>>(x, A_lora, xa);
    fgemm_kernel<<<(M_DIM / 64) * (N_DIM / 64), 256, 0, stream>>>(x, W, bias, B_lora, dbias, xa, out);
  }
}

// Round 3
// 557.921 us; speedup vs baseline: 1.1276x; 1.1276x over previous
//
#include <hip/hip_runtime.h>
#include <stdint.h>

#define M_DIM 8192
#define N_DIM 4096
#define K_DIM 4096

typedef __attribute__((ext_vector_type(4))) float f32x4;
typedef __attribute__((ext_vector_type(8))) __bf16 bf16x8;

__device__ __forceinline__ unsigned short f2bf(float f) {
  unsigned int u = __builtin_bit_cast(unsigned int, f);
  u += 0x7FFFu + ((u >> 16) & 1u);   // round-to-nearest-even
  return (unsigned short)(u >> 16);
}

__device__ __forceinline__ void load16_lds(const void* g, void* l) {
  __builtin_amdgcn_global_load_lds(
      (__attribute__((address_space(1))) void*)g,
      (__attribute__((address_space(3))) void*)l,
      16, 0, 0);
}

#define WAITVM(N) asm volatile("s_waitcnt vmcnt(" #N ")" ::: "memory")
#define BARRIER() asm volatile("s_barrier" ::: "memory")

// ---------------------------------------------------------------------------
// Kernel 1: x f32 -> bf16 (vectorized 8 elems/thread)
// ---------------------------------------------------------------------------
__global__ __launch_bounds__(256) void cvt_x_kernel(const float* __restrict__ x,
                                                    unsigned short* __restrict__ xb) {
  const int n8 = (M_DIM * K_DIM) / 8;
  int i = blockIdx.x * blockDim.x + threadIdx.x;
  const int stride = gridDim.x * blockDim.x;
  for (; i < n8; i += stride) {
    const float4* p = (const float4*)x + (size_t)i * 2;
    const float4 a = p[0];
    const float4 b = p[1];
    uint4 o;
    o.x = (unsigned)f2bf(a.x) | ((unsigned)f2bf(a.y) << 16);
    o.y = (unsigned)f2bf(a.z) | ((unsigned)f2bf(a.w) << 16);
    o.z = (unsigned)f2bf(b.x) | ((unsigned)f2bf(b.y) << 16);
    o.w = (unsigned)f2bf(b.z) | ((unsigned)f2bf(b.w) << 16);
    ((uint4*)xb)[i] = o;
  }
}

// ---------------------------------------------------------------------------
// Kernel 2: Wb[o][i] = bf16(W[o][i] + 2 * sum_r B[o][r]*A[r][i])
// ---------------------------------------------------------------------------
__global__ __launch_bounds__(256) void build_wb_kernel(const float* __restrict__ W,
                                                       const float* __restrict__ B_lora,
                                                       const float* __restrict__ A_lora,
                                                       unsigned short* __restrict__ wb) {
  __shared__ float As[64][17];
  __shared__ float Bs[64][17];
  const int t = threadIdx.x;
  const int i0 = blockIdx.x * 64;
  const int o0 = blockIdx.y * 64;
  {
    const int c = t & 63;
    #pragma unroll
    for (int rr = (t >> 6); rr < 16; rr += 4)
      As[c][rr] = A_lora[rr * K_DIM + i0 + c];
    const int r2 = t & 15;
    #pragma unroll
    for (int oo = (t >> 4); oo < 64; oo += 16)
      Bs[oo][r2] = B_lora[(o0 + oo) * 16 + r2];
  }
  __syncthreads();
  const int ci = t & 63;
  const int og = t >> 6;
  float areg[16];
  #pragma unroll
  for (int r = 0; r < 16; ++r) areg[r] = As[ci][r];
  const int i = i0 + ci;
  #pragma unroll 4
  for (int j = 0; j < 16; ++j) {
    const int ol = og * 16 + j;
    float d = 0.f;
    #pragma unroll
    for (int r = 0; r < 16; ++r) d += Bs[ol][r] * areg[r];
    const size_t idx = (size_t)(o0 + ol) * K_DIM + i;
    wb[idx] = f2bf(W[idx] + 2.0f * d);
  }
}

// ---------------------------------------------------------------------------
// Kernel 3: 256x256 8-phase bf16 MFMA GEMM (T2+T3+T4+T5), BK=64, 8 waves.
// out[m][n] = sum_k xb[m][k]*wb[n][k] + bias[n] + 2*dbias[n]
//
// LDS (STATIC 128 KiB): A[2][256 rows][64 bf16] linear-by-global-row;
// B[2][256][64] with rows PERMUTED so each read-half (nh) is contiguous:
//   LDS row r' bits -> global row gr: gr[4:0]=r'[4:0], gr[5]=r'[7],
//   gr[7:6]=r'[6:5]  (bit permutation => bijective)
// XOR swizzle (row&7)<<4 on the 8x16B slots of each 128B row; inverse applied
// to the per-lane global source chunk (both-sides involution, rule #21).
// Half-tile staging order per K-tile: A0,B0,B1,A1 (2 loads/phase);
// consume A0+B0 @ph1, B1 @ph2, A1 @ph3. Counted waits vmcnt(4) at ph1/2/4;
// final tile drains 4 -> 2 -> 0.
// ---------------------------------------------------------------------------
__global__ __launch_bounds__(512, 2) void gemm_kernel(const unsigned short* __restrict__ xb,
                                                      const unsigned short* __restrict__ wb,
                                                      const float* __restrict__ bias,
                                                      const float* __restrict__ dbias,
                                                      float* __restrict__ out) {
  constexpr int BK = 64;
  constexpr int NT = K_DIM / BK;                     // 64
  __shared__ char As[65536];                         // 2 x 32KB (static: no dyn-LDS limit risk)
  __shared__ char Bs[65536];                         // 2 x 32KB

  const int t = threadIdx.x;
  const int w = t >> 6, l = t & 63;
  const int wr = w >> 2, wc = w & 3;                 // 2M x 4N waves
  constexpr int NBN = N_DIM / 256;                   // 16
  constexpr int NWG = (M_DIM / 256) * NBN;           // 512 (div by 8)
  int bid = (int)blockIdx.x;
  bid = (bid & 7) * (NWG >> 3) + (bid >> 3);         // bijective XCD swizzle
  const int m0 = (bid / NBN) * 256;
  const int n0 = (bid % NBN) * 256;

  // ---- staging constants (per thread) ----
  const int trow = t >> 3;                           // 0..63
  const int scol = ((t & 7) ^ (trow & 7)) * 8;       // inverse-swizzled src chunk
  // A load slot j covers global rows rowoffA[j]+[0,64) -> LDS byte ldsoffA[j]
  const int rowoffA[4] = {0, 128, 64, 192};          // slots: A0={0,1} A1={2,3}
  const int ldsoffA[4] = {0, 16384, 8192, 24576};
  const unsigned short* gAp[4];
  #pragma unroll
  for (int j = 0; j < 4; ++j)
    gAp[j] = xb + (size_t)(m0 + rowoffA[j] + trow) * K_DIM + scol;
  // B load slot j covers LDS rows j*64+[0,64); global row via permutation
  const unsigned short* gBp[4];
  #pragma unroll
  for (int j = 0; j < 4; ++j) {
    const int rp = j * 64 + trow;
    const int gr = (rp & 31) + ((rp >> 5) & 3) * 64 + (rp >> 7) * 32;
    gBp[j] = wb + (size_t)(n0 + gr) * K_DIM + scol;
  }
  const int wlds = w * 1024;                         // wave-uniform lane block

  // ---- ds_read constants ----
  const int swz = (l & 7) << 4;
  const int rdk = (l >> 4) * 16;
  const int rdA = (wr * 128 + (l & 15)) * 128;       // A frag base (bytes)
  const int rdB = (wc * 32 + (l & 15)) * 128;        // B frag base (bytes)

  f32x4 acc[8][4];
  #pragma unroll
  for (int i = 0; i < 8; ++i)
    #pragma unroll
    for (int j = 0; j < 4; ++j) acc[i][j] = f32x4{0.f, 0.f, 0.f, 0.f};
  bf16x8 af[4][2], bf[4][2];

#define STAGE_A(CUR, SLOT, KT) \
  load16_lds(gAp[SLOT] + (KT), As + (CUR) * 32768 + ldsoffA[SLOT] + wlds)
#define STAGE_B(CUR, SLOT, KT) \
  load16_lds(gBp[SLOT] + (KT), Bs + (CUR) * 32768 + (SLOT) * 8192 + wlds)

#define READ_AH(CUR, MH)                                                      \
  {                                                                           \
    const char* base_ = As + (CUR) * 32768 + rdA + (MH) * 8192;               \
    _Pragma("unroll") for (int mf_ = 0; mf_ < 4; ++mf_)                       \
      _Pragma("unroll") for (int ks_ = 0; ks_ < 2; ++ks_)                     \
        af[mf_][ks_] = *(const bf16x8*)(base_ + mf_ * 2048 +                  \
                                        ((ks_ * 64 + rdk) ^ swz));            \
  }
#define READ_BH(CUR, NH)                                                      \
  {                                                                           \
    const char* base_ = Bs + (CUR) * 32768 + rdB + (NH) * 16384;              \
    _Pragma("unroll") for (int nf_ = 0; nf_ < 2; ++nf_)                       \
      _Pragma("unroll") for (int ks_ = 0; ks_ < 2; ++ks_)                     \
        bf[(NH) * 2 + nf_][ks_] = *(const bf16x8*)(base_ + nf_ * 2048 +       \
                                                   ((ks_ * 64 + rdk) ^ swz)); \
  }
#define QUAD(MH, NH)                                                          \
  {                                                                           \
    __builtin_amdgcn_s_setprio(1);                                            \
    _Pragma("unroll") for (int mf_ = 0; mf_ < 4; ++mf_)                       \
      _Pragma("unroll") for (int nf_ = 0; nf_ < 2; ++nf_)                     \
        _Pragma("unroll") for (int ks_ = 0; ks_ < 2; ++ks_)                   \
          acc[(MH) * 4 + mf_][(NH) * 2 + nf_] =                               \
              __builtin_amdgcn_mfma_f32_16x16x32_bf16(                        \
                  af[mf_][ks_], bf[(NH) * 2 + nf_][ks_],                      \
                  acc[(MH) * 4 + mf_][(NH) * 2 + nf_], 0, 0, 0);              \
    __builtin_amdgcn_s_setprio(0);                                            \
  }

  // ---- prologue: stage tile 0 in half-tile order, counted wait ----
  STAGE_A(0, 0, 0); STAGE_A(0, 1, 0);
  STAGE_B(0, 0, 0); STAGE_B(0, 1, 0);
  STAGE_B(0, 2, 0); STAGE_B(0, 3, 0);
  STAGE_A(0, 2, 0); STAGE_A(0, 3, 0);
  WAITVM(4);   // A0,B0 of tile 0 landed (B1,A1 may be in flight)
  BARRIER();

  int cur = 0;
  for (int kt = 0; kt < NT - 1; ++kt) {
    const int kn = (kt + 1) * BK;
    const int nxt = cur ^ 1;
    // phase 1: quadrant (0,0); stage A0(t+1)
    READ_AH(cur, 0); READ_BH(cur, 0);
    STAGE_A(nxt, 0, kn); STAGE_A(nxt, 1, kn);
    BARRIER(); QUAD(0, 0); WAITVM(4); BARRIER();   // B1(t) landed
    // phase 2: (0,1); stage B0(t+1)
    READ_BH(cur, 1);
    STAGE_B(nxt, 0, kn); STAGE_B(nxt, 1, kn);
    BARRIER(); QUAD(0, 1); WAITVM(4); BARRIER();   // A1(t) landed
    // phase 3: (1,1); stage B1(t+1)
    READ_AH(cur, 1);
    STAGE_B(nxt, 2, kn); STAGE_B(nxt, 3, kn);
    BARRIER(); QUAD(1, 1); BARRIER();
    // phase 4: (1,0) from held bf[0..1]; stage A1(t+1)
    STAGE_A(nxt, 2, kn); STAGE_A(nxt, 3, kn);
    BARRIER(); QUAD(1, 0); WAITVM(4); BARRIER();   // A0,B0(t+1) landed
    cur = nxt;
  }
  // ---- final tile: no staging; drain 4 -> 2 -> 0 ----
  READ_AH(cur, 0); READ_BH(cur, 0);
  BARRIER(); QUAD(0, 0); WAITVM(2); BARRIER();
  READ_BH(cur, 1);
  BARRIER(); QUAD(0, 1); WAITVM(0); BARRIER();
  READ_AH(cur, 1);
  QUAD(1, 1); QUAD(1, 0);

  // ---- epilogue: C/D layout col=l&15, row=4*(l>>4)+j ----
  float bv[4];
  #pragma unroll
  for (int nf = 0; nf < 4; ++nf) {
    const int c = n0 + wc * 64 + nf * 16 + (l & 15);
    bv[nf] = bias[c] + 2.0f * dbias[c];
  }
  #pragma unroll
  for (int mf = 0; mf < 8; ++mf) {
    const int r0 = m0 + wr * 128 + mf * 16 + ((l >> 4) << 2);
    #pragma unroll
    for (int nf = 0; nf < 4; ++nf) {
      const int c = n0 + wc * 64 + nf * 16 + (l & 15);
      const f32x4 v = acc[mf][nf];
      #pragma unroll
      for (int j = 0; j < 4; ++j)
        out[(size_t)(r0 + j) * N_DIM + c] = v[j] + bv[nf];
    }
  }
#undef STAGE_A
#undef STAGE_B
#undef READ_AH
#undef READ_BH
#undef QUAD
}

// ---------------------------------------------------------------------------
// Fallback path (tiny workspace): xa = x @ A^T, then f32 VALU GEMM + epilogue
// ---------------------------------------------------------------------------
__global__ __launch_bounds__(256) void xa_kernel(const float* __restrict__ x,
                                                 const float* __restrict__ A_lora,
                                                 float* __restrict__ xa) {
  const int m = blockIdx.x;
  const int t = threadIdx.x;
  float acc[16];
  #pragma unroll
  for (int r = 0; r < 16; ++r) acc[r] = 0.f;
  const float* xr = x + (size_t)m * K_DIM;
  for (int k = t; k < K_DIM; k += 256) {
    const float xv = xr[k];
    #pragma unroll
    for (int r = 0; r < 16; ++r) acc[r] += xv * A_lora[r * K_DIM + k];
  }
  __shared__ float red[16][4];
  #pragma unroll
  for (int r = 0; r < 16; ++r) {
    float v = acc[r];
    for (int off = 32; off > 0; off >>= 1) v += __shfl_down(v, off, 64);
    if ((t & 63) == 0) red[r][t >> 6] = v;
  }
  __syncthreads();
  if (t < 16) xa[(size_t)m * 16 + t] = red[t][0] + red[t][1] + red[t][2] + red[t][3];
}

__global__ __launch_bounds__(256) void fgemm_kernel(const float* __restrict__ x,
                                                    const float* __restrict__ W,
                                                    const float* __restrict__ bias,
                                                    const float* __restrict__ B_lora,
                                                    const float* __restrict__ dbias,
                                                    const float* __restrict__ xa,
                                                    float* __restrict__ out) {
  __shared__ float As[64][17];
  __shared__ float Ws[64][17];
  const int t = threadIdx.x;
  const int m0 = (blockIdx.x >> 6) * 64;
  const int n0 = (blockIdx.x & 63) * 64;
  const int tx = t & 15, ty = t >> 4;
  float c[4][4] = {};
  for (int kt = 0; kt < K_DIM; kt += 16) {
    #pragma unroll
    for (int e = 0; e < 4; ++e) {
      const int q = t + e * 256;
      const int r = q >> 4, k = q & 15;
      As[r][k] = x[(size_t)(m0 + r) * K_DIM + kt + k];
      Ws[r][k] = W[(size_t)(n0 + r) * K_DIM + kt + k];
    }
    __syncthreads();
    #pragma unroll
    for (int k = 0; k < 16; ++k) {
      float a[4], b[4];
      #pragma unroll
      for (int ii = 0; ii < 4; ++ii) a[ii] = As[ty * 4 + ii][k];
      #pragma unroll
      for (int jj = 0; jj < 4; ++jj) b[jj] = Ws[tx * 4 + jj][k];
      #pragma unroll
      for (int ii = 0; ii < 4; ++ii)
        #pragma unroll
        for (int jj = 0; jj < 4; ++jj) c[ii][jj] += a[ii] * b[jj];
    }
    __syncthreads();
  }
  #pragma unroll
  for (int ii = 0; ii < 4; ++ii) {
    const int row = m0 + ty * 4 + ii;
    #pragma unroll
    for (int jj = 0; jj < 4; ++jj) {
      const int col = n0 + tx * 4 + jj;
      float d = 0.f;
      #pragma unroll
      for (int r = 0; r < 16; ++r) d += xa[(size_t)row * 16 + r] * B_lora[col * 16 + r];
      out[(size_t)row * N_DIM + col] = c[ii][jj] + 2.0f * d + bias[col] + 2.0f * dbias[col];
    }
  }
}

// ---------------------------------------------------------------------------
extern "C" void kernel_launch(void* const* d_in, const int* in_sizes, int n_in,
                              void* d_out, int out_size, void* d_ws, size_t ws_size,
                              hipStream_t stream) {
  const float* x = (const float*)d_in[0];
  const float* W = (const float*)d_in[1];
  const float* bias = (const float*)d_in[2];
  const float* B_lora = (const float*)d_in[3];
  const float* A_lora = (const float*)d_in[4];
  const float* dbias = (const float*)d_in[5];
  float* out = (float*)d_out;

  const size_t NEED = (size_t)M_DIM * K_DIM * 2 + (size_t)N_DIM * K_DIM * 2;  // 96 MiB
  if (ws_size >= NEED) {
    unsigned short* xb = (unsigned short*)d_ws;
    unsigned short* wb = xb + (size_t)M_DIM * K_DIM;
    cvt_x_kernel<<<2048, 256, 0, stream>>>(x, xb);
    build_wb_kernel<<<dim3(64, 64), 256, 0, stream>>>(W, B_lora, A_lora, wb);
    gemm_kernel<<<(M_DIM / 256) * (N_DIM / 256), 512, 0, stream>>>(xb, wb, bias, dbias, out);
  } else {
    float* xa = (float*)d_ws;
    xa_kernel<<<M_DIM, 256, 0, stream>>>(x, A_lora, xa);
    fgemm_kernel<<<(M_DIM / 64) * (N_DIM / 64), 256, 0, stream>>>(x, W, bias, B_lora, dbias, xa, out);
  }
}